// Round 12
// baseline (328.239 us; speedup 1.0000x reference)
//
#include <hip/hip_runtime.h>
#include <hip/hip_bf16.h>
#include <math.h>

#define GG 64
#define NPGc 512
#define NN (GG*NPGc)      // 32768 nodes
#define EE (NN*8)         // 262144 edges
#define HH 64
#define NL 3

typedef __attribute__((ext_vector_type(8))) short short8b;
typedef __attribute__((ext_vector_type(4))) float f32x4;

// ---------------- bf16 split helpers ----------------
__device__ __forceinline__ unsigned short f2bf_rne(float f){
  unsigned u = __float_as_uint(f);
  unsigned r = u + 0x7fffu + ((u>>16)&1u);
  return (unsigned short)(r>>16);
}
__device__ __forceinline__ float bf2f(unsigned short h){
  return __uint_as_float(((unsigned)h)<<16);
}
__device__ __forceinline__ void mk_frag(const float4 &u, const float4 &v, short8b &hi, short8b &lo){
  float av[8] = {u.x,u.y,u.z,u.w,v.x,v.y,v.z,v.w};
#pragma unroll
  for (int j=0;j<8;j++){
    __hip_bfloat16 h = __float2bfloat16(av[j]);
    hi[j] = (short)__builtin_bit_cast(unsigned short, h);
    float rem = av[j] - __bfloat162float(h);
    __hip_bfloat16 l = __float2bfloat16(rem);
    lo[j] = (short)__builtin_bit_cast(unsigned short, l);
  }
}

// ---------------- threefry2x32 (JAX-compatible, partitionable mode) ----------------
__device__ __forceinline__ unsigned rotl32(unsigned x, int r){ return (x<<r)|(x>>(32-r)); }
__device__ __forceinline__ void threefry(unsigned k0, unsigned k1, unsigned x0, unsigned x1,
                                         unsigned &o0, unsigned &o1){
  unsigned ks2 = k0 ^ k1 ^ 0x1BD11BDAu;
  unsigned v0 = x0 + k0, v1 = x1 + k1;
#define R4(a,b,c,d) v0+=v1; v1=rotl32(v1,a); v1^=v0; v0+=v1; v1=rotl32(v1,b); v1^=v0; \
                    v0+=v1; v1=rotl32(v1,c); v1^=v0; v0+=v1; v1=rotl32(v1,d); v1^=v0;
  R4(13,15,26,6)  v0+=k1;  v1+=ks2+1u;
  R4(17,29,16,24) v0+=ks2; v1+=k0+2u;
  R4(13,15,26,6)  v0+=k0;  v1+=k1+3u;
  R4(17,29,16,24) v0+=k1;  v1+=ks2+4u;
  R4(13,15,26,6)  v0+=ks2; v1+=k0+5u;
#undef R4
  o0=v0; o1=v1;
}

// ---------------- node encoder ----------------
template<int K>
__global__ __launch_bounds__(256) void encode_kernel(const float* __restrict__ in,
    const float* __restrict__ w, const float* __restrict__ b,
    float* __restrict__ out, int rows)
{
  int wid = blockIdx.x*4 + (threadIdx.x>>6);
  int lane = threadIdx.x & 63;
  if (wid >= rows) return;
  const float* xr = in + (size_t)wid*K;
  float acc = b[lane];
#pragma unroll
  for (int i=0;i<K;i++) acc = fmaf(xr[i], w[i*64+lane], acc);
  out[(size_t)wid*64+lane] = fmaxf(acc, 0.f);
}

__global__ __launch_bounds__(256) void initu_kernel(const float* __restrict__ iu, float* __restrict__ u){
  int i = blockIdx.x*256 + threadIdx.x;
  if (i < GG*64) u[i] = iu[i & 63];
}

// ---------------- CSR build ----------------
__global__ __launch_bounds__(256) void count_kernel(const int* __restrict__ dst, int* __restrict__ cnt){
  int e = blockIdx.x*256 + threadIdx.x;
  if (e < EE) atomicAdd(&cnt[dst[e]], 1);
}
__global__ __launch_bounds__(1024) void scan_kernel(const int* __restrict__ cnt, int* __restrict__ indptr){
  __shared__ int part[1024];
  const int t = threadIdx.x;
  const int base = t*32;
  int s = 0;
  for (int i=0;i<32;i++) s += cnt[base+i];
  part[t] = s;
  __syncthreads();
  for (int off=1; off<1024; off<<=1){
    int v = part[t];
    int add = (t >= off) ? part[t-off] : 0;
    __syncthreads();
    part[t] = v + add;
    __syncthreads();
  }
  int run = (t==0) ? 0 : part[t-1];
  for (int i=0;i<32;i++){ indptr[base+i] = run; run += cnt[base+i]; }
  if (t==1023) indptr[NN] = run;
}
__global__ __launch_bounds__(256) void fill_kernel(const int* __restrict__ dst, const int* __restrict__ indptr,
                                                   int* __restrict__ fillc, int* __restrict__ eord){
  int e = blockIdx.x*256 + threadIdx.x;
  if (e < EE){ int dn = dst[e]; int p = atomicAdd(&fillc[dn], 1); eord[indptr[dn]+p] = e; }
}
__global__ __launch_bounds__(256) void sort_kernel(const int* __restrict__ indptr, int* __restrict__ eord){
  int n = blockIdx.x*256 + threadIdx.x;
  if (n >= NN) return;
  int lo = indptr[n], hi = indptr[n+1];
  for (int i=lo+1;i<hi;i++){
    int v = eord[i]; int j = i-1;
    while (j >= lo && eord[j] > v){ eord[j+1]=eord[j]; j--; }
    eord[j+1] = v;
  }
}
__global__ __launch_bounds__(256) void perm_kernel(const int* __restrict__ src, const int* __restrict__ dst,
                                                   const int* __restrict__ eord,
                                                   int* __restrict__ srcs, int* __restrict__ dsts){
  int p = blockIdx.x*256 + threadIdx.x;
  if (p < EE){ int e = eord[p]; srcs[p] = src[e]; dsts[p] = dst[e]; }
}

// ---------------- pre_kernel: oa = x@wa, ob = x@wb (layer 0 only) ----------------
__global__ __launch_bounds__(256) void pre_kernel(const float* __restrict__ x,
    const float* __restrict__ wa, const float* __restrict__ wb,
    float* __restrict__ oa, float* __restrict__ ob, int rows)
{
  __shared__ float4 xs4[32*17];
  __shared__ float4 wsa[1024], wsb[1024];
  const int t = threadIdx.x;
  const int rowbase = blockIdx.x*32;
  {
    const int gi16 = t>>4, lg = t&15;
#pragma unroll
    for (int it=0; it<2; ++it){
      int er = gi16 + (it<<4);
      xs4[er*17+lg] = ((const float4*)(x + (size_t)64*(rowbase+er)))[lg];
    }
  }
  const float4* wa4 = (const float4*)wa;
  const float4* wb4 = (const float4*)wb;
#pragma unroll
  for (int i=0;i<4;i++){ wsa[t+i*256] = wa4[t+i*256]; wsb[t+i*256] = wb4[t+i*256]; }
  __syncthreads();

  const int r0 = (t>>4)*2, cq = t&15;
  float accA[2][4] = {{0,0,0,0},{0,0,0,0}};
  float accB[2][4] = {{0,0,0,0},{0,0,0,0}};
#pragma unroll
  for (int k4=0;k4<16;k4++){
    float4 a0 = xs4[(r0  )*17 + k4];
    float4 a1 = xs4[(r0+1)*17 + k4];
    const float* a0p = (const float*)&a0;
    const float* a1p = (const float*)&a1;
#pragma unroll
    for (int kk=0;kk<4;kk++){
      float4 ba = wsa[(k4*4+kk)*16 + cq];
      float4 bb = wsb[(k4*4+kk)*16 + cq];
      accA[0][0]=fmaf(a0p[kk],ba.x,accA[0][0]); accA[0][1]=fmaf(a0p[kk],ba.y,accA[0][1]);
      accA[0][2]=fmaf(a0p[kk],ba.z,accA[0][2]); accA[0][3]=fmaf(a0p[kk],ba.w,accA[0][3]);
      accA[1][0]=fmaf(a1p[kk],ba.x,accA[1][0]); accA[1][1]=fmaf(a1p[kk],ba.y,accA[1][1]);
      accA[1][2]=fmaf(a1p[kk],ba.z,accA[1][2]); accA[1][3]=fmaf(a1p[kk],ba.w,accA[1][3]);
      accB[0][0]=fmaf(a0p[kk],bb.x,accB[0][0]); accB[0][1]=fmaf(a0p[kk],bb.y,accB[0][1]);
      accB[0][2]=fmaf(a0p[kk],bb.z,accB[0][2]); accB[0][3]=fmaf(a0p[kk],bb.w,accB[0][3]);
      accB[1][0]=fmaf(a1p[kk],bb.x,accB[1][0]); accB[1][1]=fmaf(a1p[kk],bb.y,accB[1][1]);
      accB[1][2]=fmaf(a1p[kk],bb.z,accB[1][2]); accB[1][3]=fmaf(a1p[kk],bb.w,accB[1][3]);
    }
  }
#pragma unroll
  for (int rr=0; rr<2; rr++){
    size_t row = rowbase + r0 + rr;
    float4 va = {accA[rr][0],accA[rr][1],accA[rr][2],accA[rr][3]};
    float4 vb = {accB[rr][0],accB[rr][1],accB[rr][2],accB[rr][3]};
    ((float4*)(oa + row*64))[cq] = va;
    ((float4*)(ob + row*64))[cq] = vb;
  }
}

// ---------------- weight prep: per-lane MFMA B-fragments (bf16 hi/lo) ----------------
__global__ __launch_bounds__(256) void wprep_kernel(const float* __restrict__ edge_w,
    const float* __restrict__ ew1, const float* __restrict__ ew2,
    const float* __restrict__ nw1, const float* __restrict__ nw2,
    short* __restrict__ wfhi, short* __restrict__ wflo)
{
  int b = blockIdx.x;
  const float* W; int K; int kc; size_t doff;
  if (b < 31){
    int m = 0; kc = 0; doff = 0; int rem = b;
    for (m = 0; m < 13; m++){
      int kcs = (m==0) ? 1 : ((((m-1)&3)==2) ? 4 : 2);
      if (rem < kcs){ kc = rem; break; }
      rem -= kcs; doff += (size_t)kcs*2048;
    }
    if (m == 0){ W = edge_w; K = 16; }
    else {
      int l = (m-1)>>2, r = (m-1)&3;
      if      (r==0){ W = ew1 + (size_t)l*16384 + 8192; K = 64;  }
      else if (r==1){ W = ew2 + (size_t)l*4096;         K = 64;  }
      else if (r==2){ W = nw1 + (size_t)l*12288;        K = 128; }
      else          { W = nw2 + (size_t)l*4096;         K = 64;  }
    }
  } else {
    int idx = b - 31;
    int mi = idx >> 1; kc = idx & 1;
    int l = mi >> 1, which = mi & 1;
    W = ew1 + (size_t)l*16384 + (size_t)which*4096; K = 64;
    doff = 63488 + (size_t)mi*4096;
  }
  const int nt = threadIdx.x>>6, lane = threadIdx.x&63;
#pragma unroll
  for (int j=0;j<8;j++){
    int k = kc*32 + (lane>>4)*8 + j;
    int n = nt*16 + (lane&15);
    float v = (k < K) ? W[k*64+n] : 0.f;
    size_t o = doff + (size_t)kc*2048 + (size_t)((nt*64+lane)*8+j);
    unsigned short hi = f2bf_rne(v);
    wfhi[o] = (short)hi;
    wflo[o] = (short)f2bf_rne(v - bf2f(hi));
  }
}

// ---------------- edge MLP: 8 waves/block, LDS-staged weights, per-wave 16-edge slices ----------------
// 512 threads, 128 edges/block, 2048 blocks. Slice id = bid*8 + wv (16384 slices, same as before).
template<int FUSE, int WRITE_HE>
__global__ __launch_bounds__(512) void edge_mlp_mfma(
    const float* __restrict__ he, const float* __restrict__ eattr,
    const int* __restrict__ eord,
    const float* __restrict__ pa, const float* __restrict__ pb,
    const float* __restrict__ ue,
    const int* __restrict__ srcs, const int* __restrict__ dsts,
    const int* __restrict__ indptr,
    const short* __restrict__ weh, const short* __restrict__ wel,
    const short* __restrict__ w1h, const short* __restrict__ w1l,
    const short* __restrict__ w2h, const short* __restrict__ w2l,
    const float* __restrict__ eb, const float* __restrict__ b1,
    const float* __restrict__ b2,
    const float* __restrict__ lng, const float* __restrict__ lnb,
    float* __restrict__ outp,
    float* __restrict__ aggp, float* __restrict__ headp, float* __restrict__ tailp)
{
  __shared__ float4 xs4[128*17];              // 128 rows, stride 17 float4 (34816 B)
  __shared__ short  wlds[4*4096];             // W1h|W1l|W2h|W2l fragments (32 KB)
  __shared__ short  ewlds[FUSE ? 2*2048 : 4]; // enc weights (8 KB, l0 only)
  __shared__ float4 eas[FUSE ? 128*4 : 1];    // gathered eattr rows (8 KB, l0 only)

  const int t = threadIdx.x;
  const int bid = ((blockIdx.x & 7) << 8) | (blockIdx.x >> 3);  // XCD swizzle, 2048 = 8*256
  const int rowbase = bid*128;
  const int g = rowbase >> 12;
  const int wv = t>>6, lane = t&63, cl = lane&15, kgrp = lane>>4;
  const int sbase = rowbase + 16*wv;
  const int sid   = bid*8 + wv;
  const int lrow  = 16*wv + cl;
  const int grow0 = sbase + 4*kgrp;

  // ---- stage weight fragments into LDS (coalesced int4) ----
  {
    const int4* s1h = (const int4*)w1h; const int4* s1l = (const int4*)w1l;
    const int4* s2h = (const int4*)w2h; const int4* s2l = (const int4*)w2l;
    int4* d = (int4*)wlds;
    d[t]        = s1h[t];
    d[512 + t]  = s1l[t];
    d[1024 + t] = s2h[t];
    d[1536 + t] = s2l[t];
    if constexpr (FUSE){
      int4* de = (int4*)ewlds;
      if (t < 256)       de[t] = ((const int4*)weh)[t];
      else if (t < 512)  de[t] = ((const int4*)wel)[t-256];
    }
  }

  // register-resident params
  float b1c[4], b2c[4], lngc[4], lnbc[4], uec[4], ebc[4];
#pragma unroll
  for (int nt=0;nt<4;nt++){
    int cn = nt*16 + cl;
    b1c[nt] = b1[cn]; b2c[nt] = b2[cn];
    lngc[nt] = lng[cn]; lnbc[nt] = lnb[cn];
    uec[nt] = ue[(g<<6)+cn];
    if constexpr (FUSE) ebc[nt] = eb[cn]; else ebc[nt] = 0.f;
  }

  // epilogue gathers (issued early, overlap with weight staging + GEMM1)
  int4 sv = ((const int4*)srcs)[grow0>>2];
  int4 dv = ((const int4*)dsts)[grow0>>2];
  float exa[4][4], exb[4][4];
#pragma unroll
  for (int reg=0;reg<4;reg++){
    int s_ = ((const int*)&sv)[reg], d_ = ((const int*)&dv)[reg];
#pragma unroll
    for (int nt=0;nt<4;nt++){
      exa[reg][nt] = pa[(size_t)s_*64 + nt*16 + cl];
      exb[reg][nt] = pb[(size_t)d_*64 + nt*16 + cl];
    }
  }

  float* xsw = (float*)xs4;

  if constexpr (FUSE){
    // stage eattr rows (own-wave 16 rows)
    int r = lane>>2, q = lane&3;
    int e = eord[sbase + r];
    eas[(16*wv + r)*4 + q] = ((const float4*)(eattr + (size_t)e*16))[q];
  } else {
    // stage he rows (own-wave 16 rows)
    const float4* heb = (const float4*)(he + (size_t)rowbase*64);
#pragma unroll
    for (int it=0;it<4;it++){
      int r = 16*wv + (lane>>4) + it*4;
      xs4[r*17 + cl] = heb[r*16 + cl];
    }
  }

  __syncthreads();   // weights (and eas) resident

  const short8b* W1h = (const short8b*)(wlds);
  const short8b* W1l = (const short8b*)(wlds + 4096);
  const short8b* W2h = (const short8b*)(wlds + 8192);
  const short8b* W2l = (const short8b*)(wlds + 12288);

  if constexpr (FUSE){
    // encode: he_row = relu(eattr @ We + be), K=16 (padded to 32)
    f32x4 c0={0,0,0,0}, c1={0,0,0,0}, c2={0,0,0,0}, c3={0,0,0,0};
    short8b ahi, alo;
    if (kgrp < 2){
      float4 a0 = eas[(16*wv+cl)*4 + kgrp*2];
      float4 a1 = eas[(16*wv+cl)*4 + kgrp*2 + 1];
      mk_frag(a0, a1, ahi, alo);
    } else {
      ahi = (short8b){0,0,0,0,0,0,0,0};
      alo = (short8b){0,0,0,0,0,0,0,0};
    }
    const short8b* Wh = (const short8b*)(ewlds);
    const short8b* Wl = (const short8b*)(ewlds + 2048);
#pragma unroll
    for (int nt=0;nt<4;nt++){
      short8b bh = Wh[nt*64 + lane];
      short8b bl = Wl[nt*64 + lane];
      f32x4 c = (nt==0)?c0:(nt==1)?c1:(nt==2)?c2:c3;
      c = __builtin_amdgcn_mfma_f32_16x16x32_bf16(ahi, bh, c, 0,0,0);
      c = __builtin_amdgcn_mfma_f32_16x16x32_bf16(alo, bh, c, 0,0,0);
      c = __builtin_amdgcn_mfma_f32_16x16x32_bf16(ahi, bl, c, 0,0,0);
      if (nt==0) c0=c; else if (nt==1) c1=c; else if (nt==2) c2=c; else c3=c;
    }
#pragma unroll
    for (int nt=0;nt<4;nt++){
      int cn = nt*16 + cl;
      f32x4 c = (nt==0)?c0:(nt==1)?c1:(nt==2)?c2:c3;
#pragma unroll
      for (int reg=0;reg<4;reg++){
        float h = fmaxf(c[reg] + ebc[nt], 0.f);
        xsw[(16*wv + 4*kgrp + reg)*68 + cn] = h;
      }
    }
  }

  // ---- GEMM1 ----
  f32x4 acc0 = {0,0,0,0}, acc1 = {0,0,0,0}, acc2_ = {0,0,0,0}, acc3 = {0,0,0,0};
#pragma unroll
  for (int kc=0;kc<2;kc++){
    float4 a0 = xs4[lrow*17 + kc*8 + kgrp*2];
    float4 a1 = xs4[lrow*17 + kc*8 + kgrp*2 + 1];
    short8b ahi, alo; mk_frag(a0, a1, ahi, alo);
#pragma unroll
    for (int nt=0;nt<4;nt++){
      short8b bh = W1h[(kc*4+nt)*64 + lane];
      short8b bl = W1l[(kc*4+nt)*64 + lane];
      f32x4 c = (nt==0)?acc0:(nt==1)?acc1:(nt==2)?acc2_:acc3;
      c = __builtin_amdgcn_mfma_f32_16x16x32_bf16(ahi, bh, c, 0,0,0);
      c = __builtin_amdgcn_mfma_f32_16x16x32_bf16(alo, bh, c, 0,0,0);
      c = __builtin_amdgcn_mfma_f32_16x16x32_bf16(ahi, bl, c, 0,0,0);
      if (nt==0) acc0=c; else if (nt==1) acc1=c; else if (nt==2) acc2_=c; else acc3=c;
    }
  }

  // ---- epilogue1: h1 = relu(C + b1 + ue + pa[src] + pb[dst]) -> LDS (own rows) ----
#pragma unroll
  for (int nt=0;nt<4;nt++){
    int cn = nt*16 + cl;
    float bc = b1c[nt] + uec[nt];
    f32x4 c = (nt==0)?acc0:(nt==1)?acc1:(nt==2)?acc2_:acc3;
#pragma unroll
    for (int reg=0;reg<4;reg++){
      float h = fmaxf(c[reg] + bc + exa[reg][nt] + exb[reg][nt], 0.f);
      xsw[(16*wv + 4*kgrp + reg)*68 + cn] = h;
    }
  }

  // ---- GEMM2 ----
  f32x4 d0 = {0,0,0,0}, d1 = {0,0,0,0}, d2 = {0,0,0,0}, d3 = {0,0,0,0};
#pragma unroll
  for (int kc=0;kc<2;kc++){
    float4 a0 = xs4[lrow*17 + kc*8 + kgrp*2];
    float4 a1 = xs4[lrow*17 + kc*8 + kgrp*2 + 1];
    short8b ahi, alo; mk_frag(a0, a1, ahi, alo);
#pragma unroll
    for (int nt=0;nt<4;nt++){
      short8b bh = W2h[(kc*4+nt)*64 + lane];
      short8b bl = W2l[(kc*4+nt)*64 + lane];
      f32x4 c = (nt==0)?d0:(nt==1)?d1:(nt==2)?d2:d3;
      c = __builtin_amdgcn_mfma_f32_16x16x32_bf16(ahi, bh, c, 0,0,0);
      c = __builtin_amdgcn_mfma_f32_16x16x32_bf16(alo, bh, c, 0,0,0);
      c = __builtin_amdgcn_mfma_f32_16x16x32_bf16(ahi, bl, c, 0,0,0);
      if (nt==0) d0=c; else if (nt==1) d1=c; else if (nt==2) d2=c; else d3=c;
    }
  }

  // ---- LayerNorm -> LDS (own rows) ----
#pragma unroll
  for (int reg=0;reg<4;reg++){
    float v0 = d0[reg] + b2c[0];
    float v1 = d1[reg] + b2c[1];
    float v2 = d2[reg] + b2c[2];
    float v3 = d3[reg] + b2c[3];
    float sA = v0+v1+v2+v3;
    float sB = v0*v0+v1*v1+v2*v2+v3*v3;
#pragma unroll
    for (int m=1;m<16;m<<=1){ sA += __shfl_xor(sA,m); sB += __shfl_xor(sB,m); }
    float mean = sA * 0.015625f;
    float var  = sB * 0.015625f - mean*mean;
    float inv  = 1.0f / sqrtf(var + 1e-5f);
    float* lr = xsw + (16*wv + 4*kgrp + reg)*68;
    lr[cl]    = (v0-mean)*inv*lngc[0] + lnbc[0];
    lr[16+cl] = (v1-mean)*inv*lngc[1] + lnbc[1];
    lr[32+cl] = (v2-mean)*inv*lngc[2] + lnbc[2];
    lr[48+cl] = (v3-mean)*inv*lngc[3] + lnbc[3];
  }

  // ---- he store (own rows, coalesced float4) ----
  if constexpr (WRITE_HE){
    float4* he4 = (float4*)outp;
#pragma unroll
    for (int it=0;it<4;it++){
      int r = 16*wv + (lane>>4) + it*4;
      he4[(size_t)rowbase*16 + r*16 + cl] = xs4[r*17 + cl];
    }
  }

  // ---- per-slice deterministic aggregation (own-wave LDS, no barrier) ----
  {
    int n0 = dsts[sbase], nL = dsts[sbase+15];
    const int s = lane>>4, cq2 = lane&15;
    for (int n = n0 + s; n <= nL; n += 4){
      int lo = indptr[n], hi = indptr[n+1];
      int lo_c = lo - sbase; if (lo_c < 0) lo_c = 0;
      int hi_c = hi - sbase; if (hi_c > 16) hi_c = 16;
      float4 a = {0,0,0,0};
      for (int p = lo_c; p < hi_c; ++p){
        float4 v = xs4[(16*wv+p)*17 + cq2];
        a.x += v.x; a.y += v.y; a.z += v.z; a.w += v.w;
      }
      if (lo < sbase)            ((float4*)(headp + (size_t)sid*64))[cq2] = a;
      else if (hi > sbase + 16)  ((float4*)(tailp + (size_t)sid*64))[cq2] = a;
      else                       ((float4*)(aggp + (size_t)n*64))[cq2] = a;
    }
    if (s == 0 && !(indptr[n0] < sbase)){
      float4 z = {0,0,0,0};
      ((float4*)(headp + (size_t)sid*64))[cq2] = z;
    }
    if (s == 1){
      int lo = indptr[nL], hi = indptr[nL+1];
      if (!(lo >= sbase && hi > sbase + 16)){
        float4 z = {0,0,0,0};
        ((float4*)(tailp + (size_t)sid*64))[cq2] = z;
      }
    }
  }
}

// ---------------- node MLP: barrier-free, per-wave 16-node slices ----------------
template<int PREP>
__global__ __launch_bounds__(256) void node_mlp_mfma(
    const float* __restrict__ hn, const float* __restrict__ agg,
    const float* __restrict__ un,
    const int* __restrict__ indptr,
    const float* __restrict__ headp, const float* __restrict__ tailp,
    const short* __restrict__ w1h, const short* __restrict__ w1l,
    const short* __restrict__ w2h, const short* __restrict__ w2l,
    const short* __restrict__ wah, const short* __restrict__ wal,
    const short* __restrict__ wbh, const short* __restrict__ wbl,
    const float* __restrict__ b1, const float* __restrict__ b2,
    const float* __restrict__ lng, const float* __restrict__ lnb,
    float* __restrict__ outp, float* __restrict__ pn, float* __restrict__ pe,
    float* __restrict__ pa, float* __restrict__ pb)
{
  __shared__ float4 xs4[64*33];

  const int t = threadIdx.x;
  const int bid = ((blockIdx.x & 7) << 6) | (blockIdx.x >> 3);
  const int rowbase = bid*64;
  const int g = rowbase >> 9;
  const int wv = t>>6, lane = t&63, cl = lane&15, kgrp = lane>>4;
  const int sid   = bid*4 + wv;
  const int lrow  = 16*wv + cl;
  const int grow0 = rowbase + 16*wv + 4*kgrp;

  float b1c[4], b2c[4], lngc[4], lnbc[4], unc[4];
#pragma unroll
  for (int nt=0;nt<4;nt++){
    int cn = nt*16 + cl;
    b1c[nt] = b1[cn]; b2c[nt] = b2[cn];
    lngc[nt] = lng[cn]; lnbc[nt] = lnb[cn];
    unc[nt] = un[(g<<6)+cn];
  }

  {
    const float4* hn4 = (const float4*)(hn + (size_t)rowbase*64);
#pragma unroll
    for (int it=0;it<4;it++){
      int r = 16*wv + (lane>>4) + it*4;
      xs4[r*33 + cl] = hn4[r*16 + cl];
    }
  }
  float4 easum = {0,0,0,0};
  {
#pragma unroll
    for (int it=0;it<4;it++){
      int r = 16*wv + (lane>>4) + it*4;
      int n = rowbase + r;
      int lo = indptr[n], hi = indptr[n+1];
      float4 a = {0,0,0,0};
      if (lo < hi){
        int s0 = lo >> 4, s1 = (hi-1) >> 4;
        if (s0 == s1){
          a = ((const float4*)(agg + (size_t)n*64))[cl];
        } else {
          a = ((const float4*)(tailp + (size_t)s0*64))[cl];
          for (int s = s0+1; s <= s1; ++s){
            float4 h = ((const float4*)(headp + (size_t)s*64))[cl];
            a.x+=h.x; a.y+=h.y; a.z+=h.z; a.w+=h.w;
          }
        }
      }
      xs4[r*33 + 16 + cl] = a;
      easum.x += a.x; easum.y += a.y; easum.z += a.z; easum.w += a.w;
    }
    easum.x += __shfl_xor(easum.x,16); easum.x += __shfl_xor(easum.x,32);
    easum.y += __shfl_xor(easum.y,16); easum.y += __shfl_xor(easum.y,32);
    easum.z += __shfl_xor(easum.z,16); easum.z += __shfl_xor(easum.z,32);
    easum.w += __shfl_xor(easum.w,16); easum.w += __shfl_xor(easum.w,32);
    if (kgrp == 0) ((float4*)(pe + (size_t)sid*64))[cl] = easum;
  }

  const short8b* W1h = (const short8b*)w1h;
  const short8b* W1l = (const short8b*)w1l;
  const short8b* W2h = (const short8b*)w2h;
  const short8b* W2l = (const short8b*)w2l;

  // ---- GEMM1 (K=128) ----
  f32x4 acc0 = {0,0,0,0}, acc1 = {0,0,0,0}, acc2_ = {0,0,0,0}, acc3 = {0,0,0,0};
#pragma unroll
  for (int kc=0;kc<4;kc++){
    float4 a0 = xs4[lrow*33 + kc*8 + kgrp*2];
    float4 a1 = xs4[lrow*33 + kc*8 + kgrp*2 + 1];
    short8b ahi, alo; mk_frag(a0, a1, ahi, alo);
#pragma unroll
    for (int nt=0;nt<4;nt++){
      short8b bh = W1h[(kc*4+nt)*64 + lane];
      short8b bl = W1l[(kc*4+nt)*64 + lane];
      f32x4 c = (nt==0)?acc0:(nt==1)?acc1:(nt==2)?acc2_:acc3;
      c = __builtin_amdgcn_mfma_f32_16x16x32_bf16(ahi, bh, c, 0,0,0);
      c = __builtin_amdgcn_mfma_f32_16x16x32_bf16(alo, bh, c, 0,0,0);
      c = __builtin_amdgcn_mfma_f32_16x16x32_bf16(ahi, bl, c, 0,0,0);
      if (nt==0) acc0=c; else if (nt==1) acc1=c; else if (nt==2) acc2_=c; else acc3=c;
    }
  }

  float* xsw = (float*)xs4;
#pragma unroll
  for (int nt=0;nt<4;nt++){
    int cn = nt*16 + cl;
    float bc = b1c[nt] + unc[nt];
    f32x4 c = (nt==0)?acc0:(nt==1)?acc1:(nt==2)?acc2_:acc3;
#pragma unroll
    for (int reg=0;reg<4;reg++){
      float h = fmaxf(c[reg] + bc, 0.f);
      xsw[(16*wv + 4*kgrp + reg)*132 + cn] = h;
    }
  }

  // ---- GEMM2 (K=64) ----
  f32x4 d0 = {0,0,0,0}, d1 = {0,0,0,0}, d2 = {0,0,0,0}, d3 = {0,0,0,0};
#pragma unroll
  for (int kc=0;kc<2;kc++){
    float4 a0 = xs4[lrow*33 + kc*8 + kgrp*2];
    float4 a1 = xs4[lrow*33 + kc*8 + kgrp*2 + 1];
    short8b ahi, alo; mk_frag(a0, a1, ahi, alo);
#pragma unroll
    for (int nt=0;nt<4;nt++){
      short8b bh = W2h[(kc*4+nt)*64 + lane];
      short8b bl = W2l[(kc*4+nt)*64 + lane];
      f32x4 c = (nt==0)?d0:(nt==1)?d1:(nt==2)?d2:d3;
      c = __builtin_amdgcn_mfma_f32_16x16x32_bf16(ahi, bh, c, 0,0,0);
      c = __builtin_amdgcn_mfma_f32_16x16x32_bf16(alo, bh, c, 0,0,0);
      c = __builtin_amdgcn_mfma_f32_16x16x32_bf16(ahi, bl, c, 0,0,0);
      if (nt==0) d0=c; else if (nt==1) d1=c; else if (nt==2) d2=c; else d3=c;
    }
  }

  // ---- LayerNorm -> LDS (own rows) + pn partial ----
  float ms0 = 0.f, ms1 = 0.f, ms2 = 0.f, ms3 = 0.f;
#pragma unroll
  for (int reg=0;reg<4;reg++){
    float v0 = d0[reg] + b2c[0];
    float v1 = d1[reg] + b2c[1];
    float v2 = d2[reg] + b2c[2];
    float v3 = d3[reg] + b2c[3];
    float sA = v0+v1+v2+v3;
    float sB = v0*v0+v1*v1+v2*v2+v3*v3;
#pragma unroll
    for (int m=1;m<16;m<<=1){ sA += __shfl_xor(sA,m); sB += __shfl_xor(sB,m); }
    float mean = sA * 0.015625f;
    float var  = sB * 0.015625f - mean*mean;
    float inv  = 1.0f / sqrtf(var + 1e-5f);
    float o0v = (v0-mean)*inv*lngc[0] + lnbc[0];
    float o1v = (v1-mean)*inv*lngc[1] + lnbc[1];
    float o2v = (v2-mean)*inv*lngc[2] + lnbc[2];
    float o3v = (v3-mean)*inv*lngc[3] + lnbc[3];
    float* lr = xsw + (16*wv + 4*kgrp + reg)*132;
    lr[cl] = o0v; lr[16+cl] = o1v; lr[32+cl] = o2v; lr[48+cl] = o3v;
    ms0 += o0v; ms1 += o1v; ms2 += o2v; ms3 += o3v;
  }
  ms0 += __shfl_xor(ms0,16); ms0 += __shfl_xor(ms0,32);
  ms1 += __shfl_xor(ms1,16); ms1 += __shfl_xor(ms1,32);
  ms2 += __shfl_xor(ms2,16); ms2 += __shfl_xor(ms2,32);
  ms3 += __shfl_xor(ms3,16); ms3 += __shfl_xor(ms3,32);
  if (kgrp == 0){
    pn[(size_t)sid*64 + cl]      = ms0;
    pn[(size_t)sid*64 + 16 + cl] = ms1;
    pn[(size_t)sid*64 + 32 + cl] = ms2;
    pn[(size_t)sid*64 + 48 + cl] = ms3;
  }

  {
    float4* hn4o = (float4*)outp;
#pragma unroll
    for (int it=0;it<4;it++){
      int r = 16*wv + (lane>>4) + it*4;
      hn4o[(size_t)rowbase*16 + r*16 + cl] = xs4[r*33 + cl];
    }
  }

  if constexpr (PREP){
#pragma unroll
    for (int m2=0;m2<2;m2++){
      const short8b* Wh = (const short8b*)(m2==0 ? wah : wbh);
      const short8b* Wl = (const short8b*)(m2==0 ? wal : wbl);
      f32x4 e0 = {0,0,0,0}, e1 = {0,0,0,0}, e2 = {0,0,0,0}, e3 = {0,0,0,0};
#pragma unroll
      for (int kc=0;kc<2;kc++){
        float4 a0 = xs4[lrow*33 + kc*8 + kgrp*2];
        float4 a1 = xs4[lrow*33 + kc*8 + kgrp*2 + 1];
        short8b ahi, alo; mk_frag(a0, a1, ahi, alo);
#pragma unroll
        for (int nt=0;nt<4;nt++){
          short8b bh = Wh[(kc*4+nt)*64 + lane];
          short8b bl = Wl[(kc*4+nt)*64 + lane];
          f32x4 c = (nt==0)?e0:(nt==1)?e1:(nt==2)?e2:e3;
          c = __builtin_amdgcn_mfma_f32_16x16x32_bf16(ahi, bh, c, 0,0,0);
          c = __builtin_amdgcn_mfma_f32_16x16x32_bf16(alo, bh, c, 0,0,0);
          c = __builtin_amdgcn_mfma_f32_16x16x32_bf16(ahi, bl, c, 0,0,0);
          if (nt==0) e0=c; else if (nt==1) e1=c; else if (nt==2) e2=c; else e3=c;
        }
      }
      float* dstp = (m2==0) ? pa : pb;
#pragma unroll
      for (int nt=0;nt<4;nt++){
        int cn = nt*16 + cl;
        f32x4 c = (nt==0)?e0:(nt==1)?e1:(nt==2)?e2:e3;
#pragma unroll
        for (int reg=0;reg<4;reg++)
          dstp[(size_t)(grow0+reg)*64 + cn] = c[reg];
      }
    }
  }
}

// ---------------- graphk ----------------
__global__ __launch_bounds__(64) void graphk(
    const float* __restrict__ pn, const float* __restrict__ pe,
    float* __restrict__ u,
    const float* __restrict__ w1, const float* __restrict__ b1,
    const float* __restrict__ w2, const float* __restrict__ b2,
    const float* __restrict__ lng, const float* __restrict__ lnb,
    const float* __restrict__ wue, const float* __restrict__ wun,
    float* __restrict__ ue, float* __restrict__ un)
{
  const int g = blockIdx.x, t = threadIdx.x;
  __shared__ float xin[192];
  __shared__ float h1[64];
  __shared__ float us[64];
  float uo = u[(g<<6)+t];
  float ns = 0.f, es = 0.f;
#pragma unroll
  for (int c=0;c<32;c++){
    ns += pn[(size_t)(g*32+c)*64 + t];
    es += pe[(size_t)(g*32+c)*64 + t];
  }
  xin[t] = uo; xin[64+t] = ns*(1.f/512.f); xin[128+t] = es*(1.f/4096.f);
  __syncthreads();
  float acc = b1[t];
  for (int k=0;k<192;k++) acc = fmaf(xin[k], w1[k*64+t], acc);
  h1[t] = fmaxf(acc, 0.f);
  __syncthreads();
  float v = b2[t];
  for (int k=0;k<64;k++) v = fmaf(h1[k], w2[k*64+t], v);
  float sA = v, sB = v*v;
#pragma unroll
  for (int m=1;m<64;m<<=1){ sA += __shfl_xor(sA,m); sB += __shfl_xor(sB,m); }
  float mean = sA * 0.015625f;
  float var  = sB * 0.015625f - mean*mean;
  float inv  = 1.0f / sqrtf(var + 1e-5f);
  float unew = (v-mean)*inv*lng[t] + lnb[t];
  u[(g<<6)+t] = unew;
  if (wue){
    us[t] = unew;
    __syncthreads();
    float a1 = 0.f, a2 = 0.f;
    for (int k=0;k<64;k++){
      float xv = us[k];
      a1 = fmaf(xv, wue[k*64+t], a1);
      a2 = fmaf(xv, wun[k*64+t], a2);
    }
    ue[(g<<6)+t] = a1;
    un[(g<<6)+t] = a2;
  }
}

// ---------------- heads ----------------
__global__ __launch_bounds__(512) void heads_kernel(
    const float* __restrict__ hn, const float* __restrict__ uvec,
    const float* __restrict__ aw, const float* __restrict__ ab,
    const float* __restrict__ cw, const float* __restrict__ cb,
    float* __restrict__ out)
{
  const int g = blockIdx.x, t = threadIdx.x;
  const int n = (g<<9) + t;
  const float4* hp = (const float4*)(hn + (size_t)n*64);
  const float4* ap = (const float4*)aw;
  float d = 0.f;
#pragma unroll
  for (int i=0;i<16;i++){
    float4 h = hp[i], a = ap[i];
    d += h.x*a.x + h.y*a.y + h.z*a.z + h.w*a.w;
  }
  d += ab[0];
  float z = 1.0f/(1.0f + expf(-d));

  unsigned o0,o1;
  threefry(0u, 42u, 0u, (unsigned)n, o0, o1);
  unsigned bits = o0 ^ o1;
  float f = __uint_as_float((bits>>9) | 0x3f800000u) - 1.0f;
  float gum = -logf(-logf(fmaxf(1.17549435e-38f, f)));

  const int lane = t & 63, wid = t >> 6;
  __shared__ float smax[8], ssum[8], sent[8], skey[8];
  __shared__ int   sidx[8];
  __shared__ float sM, sS;
  __shared__ int   sA;

  float m = z;
#pragma unroll
  for (int sh=1; sh<64; sh<<=1) m = fmaxf(m, __shfl_xor(m, sh));
  if (lane==0) smax[wid] = m;
  __syncthreads();
  if (t==0){ float mm=smax[0]; for(int i=1;i<8;i++) mm=fmaxf(mm,smax[i]); sM=mm; }
  __syncthreads();
  float M = sM;
  float ex = expf(z - M);
  float ssl = ex;
#pragma unroll
  for (int sh=1; sh<64; sh<<=1) ssl += __shfl_xor(ssl, sh);
  if (lane==0) ssum[wid] = ssl;
  __syncthreads();
  if (t==0){ float ss=0.f; for(int i=0;i<8;i++) ss+=ssum[i]; sS=ss; }
  __syncthreads();
  float logp = z - M - logf(sS);
  float p = expf(logp);
  float entl = p * logp;
#pragma unroll
  for (int sh=1; sh<64; sh<<=1) entl += __shfl_xor(entl, sh);
  if (lane==0) sent[wid] = entl;

  float kv = z + gum; int ki = t;
#pragma unroll
  for (int sh=1; sh<64; sh<<=1){
    float ov = __shfl_xor(kv, sh);
    int   oi = __shfl_xor(ki, sh);
    if (ov > kv || (ov == kv && oi < ki)){ kv = ov; ki = oi; }
  }
  if (lane==0){ skey[wid] = kv; sidx[wid] = ki; }
  __syncthreads();
  if (t==0){
    float bv = skey[0]; int bi = sidx[0];
    for (int i=1;i<8;i++) if (skey[i] > bv || (skey[i]==bv && sidx[i] < bi)){ bv=skey[i]; bi=sidx[i]; }
    sA = bi;
    float ent = 0.f; for (int i=0;i<8;i++) ent += sent[i];
    out[g]      = (float)bi;
    out[128+g]  = -ent;
  }
  __syncthreads();
  if (t == sA) out[64+g] = logp;

  if (t < 64){
    float pv = uvec[(g<<6)+t] * cw[t];
#pragma unroll
    for (int sh=1; sh<64; sh<<=1) pv += __shfl_xor(pv, sh);
    if (t==0) out[192+g] = pv + cb[0];
  }
}

// ---------------- launch ----------------
extern "C" void kernel_launch(void* const* d_in, const int* in_sizes, int n_in,
                              void* d_out, int out_size, void* d_ws, size_t ws_size,
                              hipStream_t stream)
{
  (void)in_sizes; (void)n_in; (void)out_size; (void)ws_size;
  const float* x      = (const float*)d_in[0];
  const float* eattr  = (const float*)d_in[1];
  const int*   eidx   = (const int*)d_in[2];
  const float* node_w = (const float*)d_in[5];
  const float* node_b = (const float*)d_in[6];
  const float* edge_w = (const float*)d_in[7];
  const float* edge_b = (const float*)d_in[8];
  const float* init_u = (const float*)d_in[9];
  const float* ew1 = (const float*)d_in[10]; const float* eb1 = (const float*)d_in[11];
  const float* ew2 = (const float*)d_in[12]; const float* eb2 = (const float*)d_in[13];
  const float* elg = (const float*)d_in[14]; const float* elb = (const float*)d_in[15];
  const float* nw1 = (const float*)d_in[16]; const float* nb1 = (const float*)d_in[17];
  const float* nw2 = (const float*)d_in[18]; const float* nb2 = (const float*)d_in[19];
  const float* nlg = (const float*)d_in[20]; const float* nlb = (const float*)d_in[21];
  const float* gw1 = (const float*)d_in[22]; const float* gb1 = (const float*)d_in[23];
  const float* gw2 = (const float*)d_in[24]; const float* gb2 = (const float*)d_in[25];
  const float* glg = (const float*)d_in[26]; const float* glb = (const float*)d_in[27];
  const float* aw  = (const float*)d_in[28]; const float* ab  = (const float*)d_in[29];
  const float* cw  = (const float*)d_in[30]; const float* cb  = (const float*)d_in[31];
  const int* src = eidx;
  const int* dst = eidx + EE;

  float* ws    = (float*)d_ws;
  float* hn    = ws;                         // N*64
  float* he    = hn + (size_t)NN*64;         // E*64  (dst-sorted order)
  float* agg   = he + (size_t)EE*64;         // N*64
  float* u     = agg + (size_t)NN*64;        // G*64
  int* cnt     = (int*)(u + GG*64);          // N
  int* indptr  = cnt + NN;                   // N+1
  int* fillc   = indptr + NN + 1;            // N
  int* eord    = fillc + NN;                 // E
  int* srcs    = eord + EE;                  // E
  int* dsts    = srcs + EE;                  // E
  float* pb    = (float*)(dsts + EE);        // N*64
  float* pa    = pb + (size_t)NN*64;         // N*64
  float* ue    = pa + (size_t)NN*64;         // G*64
  float* un    = ue + GG*64;                 // G*64
  float* pn    = un + GG*64;                 // 2048*64
  float* pe    = pn + 2048*64;               // 2048*64
  float* headp = pe + 2048*64;               // 16384*64
  float* tailp = headp + (size_t)16384*64;   // 16384*64
  short* wfh   = (short*)(tailp + (size_t)16384*64);  // 88064 shorts
  short* wfl   = wfh + 88064;                // 88064 shorts

  float* out = (float*)d_out;

  hipMemsetAsync(cnt,   0, NN*sizeof(int), stream);
  hipMemsetAsync(fillc, 0, NN*sizeof(int), stream);

  count_kernel<<<EE/256, 256, 0, stream>>>(dst, cnt);
  scan_kernel<<<1, 1024, 0, stream>>>(cnt, indptr);
  fill_kernel<<<EE/256, 256, 0, stream>>>(dst, indptr, fillc, eord);
  sort_kernel<<<NN/256, 256, 0, stream>>>(indptr, eord);
  perm_kernel<<<EE/256, 256, 0, stream>>>(src, dst, eord, srcs, dsts);

  encode_kernel<32><<<NN/4, 256, 0, stream>>>(x, node_w, node_b, hn, NN);
  initu_kernel<<<16, 256, 0, stream>>>(init_u, u);
  wprep_kernel<<<43, 256, 0, stream>>>(edge_w, ew1, ew2, nw1, nw2, wfh, wfl);

  // layer-0 pa/pb, ue/un
  pre_kernel<<<NN/32, 256, 0, stream>>>(hn, ew1, ew1 + 64*64, pa, pb, NN);
  pre_kernel<<<2, 256, 0, stream>>>(u, ew1 + 192*64, nw1 + 128*64, ue, un, GG);

  // frag offsets (shorts): enc=0; per layer l: e1=2048+l*20480, e2=+4096, n1=+8192, n2=+16384
  // prep frags: pa(l)=63488+l*8192, pb(l)=+4096
  for (int l=0; l<NL; ++l){
    size_t e1o = 2048 + (size_t)l*20480;
    size_t e2o = e1o + 4096, n1o = e1o + 8192, n2o = e1o + 16384;
    size_t pao = 63488 + (size_t)(l+1)*8192, pbo = pao + 4096;  // next layer

    if (l == 0)
      edge_mlp_mfma<1,1><<<EE/128, 512, 0, stream>>>(he, eattr, eord, pa, pb, ue, srcs, dsts, indptr,
          wfh, wfl, wfh + e1o, wfl + e1o, wfh + e2o, wfl + e2o,
          edge_b, eb1 + l*64, eb2 + l*64, elg + l*64, elb + l*64, he, agg, headp, tailp);
    else if (l == 1)
      edge_mlp_mfma<0,1><<<EE/128, 512, 0, stream>>>(he, eattr, eord, pa, pb, ue, srcs, dsts, indptr,
          wfh, wfl, wfh + e1o, wfl + e1o, wfh + e2o, wfl + e2o,
          edge_b, eb1 + l*64, eb2 + l*64, elg + l*64, elb + l*64, he, agg, headp, tailp);
    else
      edge_mlp_mfma<0,0><<<EE/128, 512, 0, stream>>>(he, eattr, eord, pa, pb, ue, srcs, dsts, indptr,
          wfh, wfl, wfh + e1o, wfl + e1o, wfh + e2o, wfl + e2o,
          edge_b, eb1 + l*64, eb2 + l*64, elg + l*64, elb + l*64, he, agg, headp, tailp);

    if (l < NL-1)
      node_mlp_mfma<1><<<NN/64, 256, 0, stream>>>(hn, agg, un, indptr, headp, tailp,
          wfh + n1o, wfl + n1o, wfh + n2o, wfl + n2o,
          wfh + pao, wfl + pao, wfh + pbo, wfl + pbo,
          nb1 + l*64, nb2 + l*64, nlg + l*64, nlb + l*64, hn, pn, pe, pa, pb);
    else
      node_mlp_mfma<0><<<NN/64, 256, 0, stream>>>(hn, agg, un, indptr, headp, tailp,
          wfh + n1o, wfl + n1o, wfh + n2o, wfl + n2o,
          nullptr, nullptr, nullptr, nullptr,
          nb1 + l*64, nb2 + l*64, nlg + l*64, nlb + l*64, hn, pn, pe, pa, pb);

    const float* wue = (l < NL-1) ? (ew1 + (size_t)(l+1)*16384 + 192*64) : nullptr;
    const float* wun = (l < NL-1) ? (nw1 + (size_t)(l+1)*12288 + 128*64) : nullptr;
    graphk<<<GG, 64, 0, stream>>>(pn, pe, u,
        gw1 + (size_t)l*192*64, gb1 + l*64, gw2 + (size_t)l*64*64, gb2 + l*64,
        glg + l*64, glb + l*64, wue, wun, ue, un);
  }

  heads_kernel<<<GG, 512, 0, stream>>>(hn, u, aw, ab, cw, cb, out);
}

// Round 13
// 310.275 us; speedup vs baseline: 1.0579x; 1.0579x over previous
//
#include <hip/hip_runtime.h>
#include <hip/hip_bf16.h>
#include <math.h>

#define GG 64
#define NPGc 512
#define NN (GG*NPGc)      // 32768 nodes
#define EE (NN*8)         // 262144 edges
#define HH 64
#define NL 3

typedef __attribute__((ext_vector_type(8))) short short8b;
typedef __attribute__((ext_vector_type(4))) float f32x4;

// ---------------- bf16 split helpers ----------------
__device__ __forceinline__ unsigned short f2bf_rne(float f){
  unsigned u = __float_as_uint(f);
  unsigned r = u + 0x7fffu + ((u>>16)&1u);
  return (unsigned short)(r>>16);
}
__device__ __forceinline__ float bf2f(unsigned short h){
  return __uint_as_float(((unsigned)h)<<16);
}
__device__ __forceinline__ void mk_frag(const float4 &u, const float4 &v, short8b &hi, short8b &lo){
  float av[8] = {u.x,u.y,u.z,u.w,v.x,v.y,v.z,v.w};
#pragma unroll
  for (int j=0;j<8;j++){
    __hip_bfloat16 h = __float2bfloat16(av[j]);
    hi[j] = (short)__builtin_bit_cast(unsigned short, h);
    float rem = av[j] - __bfloat162float(h);
    __hip_bfloat16 l = __float2bfloat16(rem);
    lo[j] = (short)__builtin_bit_cast(unsigned short, l);
  }
}

// ---------------- threefry2x32 (JAX-compatible, partitionable mode) ----------------
__device__ __forceinline__ unsigned rotl32(unsigned x, int r){ return (x<<r)|(x>>(32-r)); }
__device__ __forceinline__ void threefry(unsigned k0, unsigned k1, unsigned x0, unsigned x1,
                                         unsigned &o0, unsigned &o1){
  unsigned ks2 = k0 ^ k1 ^ 0x1BD11BDAu;
  unsigned v0 = x0 + k0, v1 = x1 + k1;
#define R4(a,b,c,d) v0+=v1; v1=rotl32(v1,a); v1^=v0; v0+=v1; v1=rotl32(v1,b); v1^=v0; \
                    v0+=v1; v1=rotl32(v1,c); v1^=v0; v0+=v1; v1=rotl32(v1,d); v1^=v0;
  R4(13,15,26,6)  v0+=k1;  v1+=ks2+1u;
  R4(17,29,16,24) v0+=ks2; v1+=k0+2u;
  R4(13,15,26,6)  v0+=k0;  v1+=k1+3u;
  R4(17,29,16,24) v0+=k1;  v1+=ks2+4u;
  R4(13,15,26,6)  v0+=ks2; v1+=k0+5u;
#undef R4
  o0=v0; o1=v1;
}

// ---------------- fused node encoder + layer-0 pa/pb ----------------
// 32 rows/block: hn = relu(x@nodeW+b); pa = hn@Wa; pb = hn@Wb
__global__ __launch_bounds__(256) void encode_pre_kernel(const float* __restrict__ x,
    const float* __restrict__ nodew, const float* __restrict__ nodeb,
    const float* __restrict__ wa, const float* __restrict__ wb,
    float* __restrict__ hn, float* __restrict__ pa, float* __restrict__ pb)
{
  __shared__ float4 xsx[32*9];          // x rows (32 floats, pad)
  __shared__ float4 hs[32*17];          // hn rows
  __shared__ float4 wsn[512];           // node_w 32x64
  __shared__ float4 wsa[1024], wsb[1024];
  __shared__ float  bsm[64];

  const int t = threadIdx.x;
  const int rowbase = blockIdx.x*32;
  if (t < 64) bsm[t] = nodeb[t];
  {
    int row = t>>3, q = t&7;
    xsx[row*9+q] = ((const float4*)(x + (size_t)32*(rowbase+row)))[q];
  }
  {
    const float4* nw4 = (const float4*)nodew;
    wsn[t] = nw4[t]; wsn[t+256] = nw4[t+256];
    const float4* wa4 = (const float4*)wa;
    const float4* wb4 = (const float4*)wb;
#pragma unroll
    for (int i=0;i<4;i++){ wsa[t+i*256] = wa4[t+i*256]; wsb[t+i*256] = wb4[t+i*256]; }
  }
  __syncthreads();

  const int r0 = (t>>4)*2, cq = t&15;
  // hn = relu(x @ nodeW + b), K=32
  {
    float acc[2][4] = {{0,0,0,0},{0,0,0,0}};
#pragma unroll
    for (int k4=0;k4<8;k4++){
      float4 a0 = xsx[(r0  )*9 + k4];
      float4 a1 = xsx[(r0+1)*9 + k4];
      const float* a0p = (const float*)&a0;
      const float* a1p = (const float*)&a1;
#pragma unroll
      for (int kk=0;kk<4;kk++){
        float4 bb = wsn[(k4*4+kk)*16 + cq];
        acc[0][0]=fmaf(a0p[kk],bb.x,acc[0][0]); acc[0][1]=fmaf(a0p[kk],bb.y,acc[0][1]);
        acc[0][2]=fmaf(a0p[kk],bb.z,acc[0][2]); acc[0][3]=fmaf(a0p[kk],bb.w,acc[0][3]);
        acc[1][0]=fmaf(a1p[kk],bb.x,acc[1][0]); acc[1][1]=fmaf(a1p[kk],bb.y,acc[1][1]);
        acc[1][2]=fmaf(a1p[kk],bb.z,acc[1][2]); acc[1][3]=fmaf(a1p[kk],bb.w,acc[1][3]);
      }
    }
#pragma unroll
    for (int rr=0;rr<2;rr++){
      float4 h;
      h.x = fmaxf(acc[rr][0]+bsm[cq*4+0], 0.f);
      h.y = fmaxf(acc[rr][1]+bsm[cq*4+1], 0.f);
      h.z = fmaxf(acc[rr][2]+bsm[cq*4+2], 0.f);
      h.w = fmaxf(acc[rr][3]+bsm[cq*4+3], 0.f);
      hs[(r0+rr)*17 + cq] = h;
      ((float4*)(hn + (size_t)(rowbase+r0+rr)*64))[cq] = h;
    }
  }
  __syncthreads();

  // pa/pb = hn @ Wa/Wb (K=64)
  float accA[2][4] = {{0,0,0,0},{0,0,0,0}};
  float accB[2][4] = {{0,0,0,0},{0,0,0,0}};
#pragma unroll
  for (int k4=0;k4<16;k4++){
    float4 a0 = hs[(r0  )*17 + k4];
    float4 a1 = hs[(r0+1)*17 + k4];
    const float* a0p = (const float*)&a0;
    const float* a1p = (const float*)&a1;
#pragma unroll
    for (int kk=0;kk<4;kk++){
      float4 ba = wsa[(k4*4+kk)*16 + cq];
      float4 bb = wsb[(k4*4+kk)*16 + cq];
      accA[0][0]=fmaf(a0p[kk],ba.x,accA[0][0]); accA[0][1]=fmaf(a0p[kk],ba.y,accA[0][1]);
      accA[0][2]=fmaf(a0p[kk],ba.z,accA[0][2]); accA[0][3]=fmaf(a0p[kk],ba.w,accA[0][3]);
      accA[1][0]=fmaf(a1p[kk],ba.x,accA[1][0]); accA[1][1]=fmaf(a1p[kk],ba.y,accA[1][1]);
      accA[1][2]=fmaf(a1p[kk],ba.z,accA[1][2]); accA[1][3]=fmaf(a1p[kk],ba.w,accA[1][3]);
      accB[0][0]=fmaf(a0p[kk],bb.x,accB[0][0]); accB[0][1]=fmaf(a0p[kk],bb.y,accB[0][1]);
      accB[0][2]=fmaf(a0p[kk],bb.z,accB[0][2]); accB[0][3]=fmaf(a0p[kk],bb.w,accB[0][3]);
      accB[1][0]=fmaf(a1p[kk],bb.x,accB[1][0]); accB[1][1]=fmaf(a1p[kk],bb.y,accB[1][1]);
      accB[1][2]=fmaf(a1p[kk],bb.z,accB[1][2]); accB[1][3]=fmaf(a1p[kk],bb.w,accB[1][3]);
    }
  }
#pragma unroll
  for (int rr=0; rr<2; rr++){
    size_t row = rowbase + r0 + rr;
    float4 va = {accA[rr][0],accA[rr][1],accA[rr][2],accA[rr][3]};
    float4 vb = {accB[rr][0],accB[rr][1],accB[rr][2],accB[rr][3]};
    ((float4*)(pa + row*64))[cq] = va;
    ((float4*)(pb + row*64))[cq] = vb;
  }
}

__global__ __launch_bounds__(256) void initu_kernel(const float* __restrict__ iu, float* __restrict__ u){
  int i = blockIdx.x*256 + threadIdx.x;
  if (i < GG*64) u[i] = iu[i & 63];
}

// ---------------- CSR build ----------------
__global__ __launch_bounds__(256) void count_kernel(const int* __restrict__ dst, int* __restrict__ cnt){
  int e = blockIdx.x*256 + threadIdx.x;
  if (e < EE) atomicAdd(&cnt[dst[e]], 1);
}
__global__ __launch_bounds__(1024) void scan_kernel(const int* __restrict__ cnt, int* __restrict__ indptr){
  __shared__ int part[1024];
  const int t = threadIdx.x;
  const int base = t*32;
  int s = 0;
  for (int i=0;i<32;i++) s += cnt[base+i];
  part[t] = s;
  __syncthreads();
  for (int off=1; off<1024; off<<=1){
    int v = part[t];
    int add = (t >= off) ? part[t-off] : 0;
    __syncthreads();
    part[t] = v + add;
    __syncthreads();
  }
  int run = (t==0) ? 0 : part[t-1];
  for (int i=0;i<32;i++){ indptr[base+i] = run; run += cnt[base+i]; }
  if (t==1023) indptr[NN] = run;
}
__global__ __launch_bounds__(256) void fill_kernel(const int* __restrict__ dst, const int* __restrict__ indptr,
                                                   int* __restrict__ fillc, int* __restrict__ eord){
  int e = blockIdx.x*256 + threadIdx.x;
  if (e < EE){ int dn = dst[e]; int p = atomicAdd(&fillc[dn], 1); eord[indptr[dn]+p] = e; }
}
// sort each node's bucket + emit permuted srcs/dsts (fused perm)
__global__ __launch_bounds__(256) void sort_kernel(const int* __restrict__ indptr, int* __restrict__ eord,
                                                   const int* __restrict__ src, const int* __restrict__ dst,
                                                   int* __restrict__ srcs, int* __restrict__ dsts){
  int n = blockIdx.x*256 + threadIdx.x;
  if (n >= NN) return;
  int lo = indptr[n], hi = indptr[n+1];
  for (int i=lo+1;i<hi;i++){
    int v = eord[i]; int j = i-1;
    while (j >= lo && eord[j] > v){ eord[j+1]=eord[j]; j--; }
    eord[j+1] = v;
  }
  for (int i=lo;i<hi;i++){
    int e = eord[i];
    srcs[i] = src[e];
    dsts[i] = dst[e];
  }
}

// ---------------- pre_kernel (u-vector variants only, rows=64) ----------------
__global__ __launch_bounds__(256) void pre_kernel(const float* __restrict__ x,
    const float* __restrict__ wa, const float* __restrict__ wb,
    float* __restrict__ oa, float* __restrict__ ob, int rows)
{
  __shared__ float4 xs4[32*17];
  __shared__ float4 wsa[1024], wsb[1024];
  const int t = threadIdx.x;
  const int rowbase = blockIdx.x*32;
  {
    const int gi16 = t>>4, lg = t&15;
#pragma unroll
    for (int it=0; it<2; ++it){
      int er = gi16 + (it<<4);
      xs4[er*17+lg] = ((const float4*)(x + (size_t)64*(rowbase+er)))[lg];
    }
  }
  const float4* wa4 = (const float4*)wa;
  const float4* wb4 = (const float4*)wb;
#pragma unroll
  for (int i=0;i<4;i++){ wsa[t+i*256] = wa4[t+i*256]; wsb[t+i*256] = wb4[t+i*256]; }
  __syncthreads();

  const int r0 = (t>>4)*2, cq = t&15;
  float accA[2][4] = {{0,0,0,0},{0,0,0,0}};
  float accB[2][4] = {{0,0,0,0},{0,0,0,0}};
#pragma unroll
  for (int k4=0;k4<16;k4++){
    float4 a0 = xs4[(r0  )*17 + k4];
    float4 a1 = xs4[(r0+1)*17 + k4];
    const float* a0p = (const float*)&a0;
    const float* a1p = (const float*)&a1;
#pragma unroll
    for (int kk=0;kk<4;kk++){
      float4 ba = wsa[(k4*4+kk)*16 + cq];
      float4 bb = wsb[(k4*4+kk)*16 + cq];
      accA[0][0]=fmaf(a0p[kk],ba.x,accA[0][0]); accA[0][1]=fmaf(a0p[kk],ba.y,accA[0][1]);
      accA[0][2]=fmaf(a0p[kk],ba.z,accA[0][2]); accA[0][3]=fmaf(a0p[kk],ba.w,accA[0][3]);
      accA[1][0]=fmaf(a1p[kk],ba.x,accA[1][0]); accA[1][1]=fmaf(a1p[kk],ba.y,accA[1][1]);
      accA[1][2]=fmaf(a1p[kk],ba.z,accA[1][2]); accA[1][3]=fmaf(a1p[kk],ba.w,accA[1][3]);
      accB[0][0]=fmaf(a0p[kk],bb.x,accB[0][0]); accB[0][1]=fmaf(a0p[kk],bb.y,accB[0][1]);
      accB[0][2]=fmaf(a0p[kk],bb.z,accB[0][2]); accB[0][3]=fmaf(a0p[kk],bb.w,accB[0][3]);
      accB[1][0]=fmaf(a1p[kk],bb.x,accB[1][0]); accB[1][1]=fmaf(a1p[kk],bb.y,accB[1][1]);
      accB[1][2]=fmaf(a1p[kk],bb.z,accB[1][2]); accB[1][3]=fmaf(a1p[kk],bb.w,accB[1][3]);
    }
  }
#pragma unroll
  for (int rr=0; rr<2; rr++){
    size_t row = rowbase + r0 + rr;
    float4 va = {accA[rr][0],accA[rr][1],accA[rr][2],accA[rr][3]};
    float4 vb = {accB[rr][0],accB[rr][1],accB[rr][2],accB[rr][3]};
    ((float4*)(oa + row*64))[cq] = va;
    ((float4*)(ob + row*64))[cq] = vb;
  }
}

// ---------------- weight prep: per-lane MFMA B-fragments (bf16 hi/lo) ----------------
__global__ __launch_bounds__(256) void wprep_kernel(const float* __restrict__ edge_w,
    const float* __restrict__ ew1, const float* __restrict__ ew2,
    const float* __restrict__ nw1, const float* __restrict__ nw2,
    short* __restrict__ wfhi, short* __restrict__ wflo)
{
  int b = blockIdx.x;
  const float* W; int K; int kc; size_t doff;
  if (b < 31){
    int m = 0; kc = 0; doff = 0; int rem = b;
    for (m = 0; m < 13; m++){
      int kcs = (m==0) ? 1 : ((((m-1)&3)==2) ? 4 : 2);
      if (rem < kcs){ kc = rem; break; }
      rem -= kcs; doff += (size_t)kcs*2048;
    }
    if (m == 0){ W = edge_w; K = 16; }
    else {
      int l = (m-1)>>2, r = (m-1)&3;
      if      (r==0){ W = ew1 + (size_t)l*16384 + 8192; K = 64;  }
      else if (r==1){ W = ew2 + (size_t)l*4096;         K = 64;  }
      else if (r==2){ W = nw1 + (size_t)l*12288;        K = 128; }
      else          { W = nw2 + (size_t)l*4096;         K = 64;  }
    }
  } else {
    int idx = b - 31;
    int mi = idx >> 1; kc = idx & 1;
    int l = mi >> 1, which = mi & 1;
    W = ew1 + (size_t)l*16384 + (size_t)which*4096; K = 64;
    doff = 63488 + (size_t)mi*4096;
  }
  const int nt = threadIdx.x>>6, lane = threadIdx.x&63;
#pragma unroll
  for (int j=0;j<8;j++){
    int k = kc*32 + (lane>>4)*8 + j;
    int n = nt*16 + (lane&15);
    float v = (k < K) ? W[k*64+n] : 0.f;
    size_t o = doff + (size_t)kc*2048 + (size_t)((nt*64+lane)*8+j);
    unsigned short hi = f2bf_rne(v);
    wfhi[o] = (short)hi;
    wflo[o] = (short)f2bf_rne(v - bf2f(hi));
  }
}

// ---------------- edge MLP: barrier-free, per-wave 16-edge slices (R11 config) ----------------
// 128 threads (2 waves), 32 edges/block. Slice id = bid*2 + wv (16384 slices).
template<int FUSE, int WRITE_HE>
__global__ __launch_bounds__(128) void edge_mlp_mfma(
    const float* __restrict__ he, const float* __restrict__ eattr,
    const int* __restrict__ eord,
    const float* __restrict__ pa, const float* __restrict__ pb,
    const float* __restrict__ ue,
    const int* __restrict__ srcs, const int* __restrict__ dsts,
    const int* __restrict__ indptr,
    const short* __restrict__ weh, const short* __restrict__ wel,
    const short* __restrict__ w1h, const short* __restrict__ w1l,
    const short* __restrict__ w2h, const short* __restrict__ w2l,
    const float* __restrict__ eb, const float* __restrict__ b1,
    const float* __restrict__ b2,
    const float* __restrict__ lng, const float* __restrict__ lnb,
    float* __restrict__ outp,
    float* __restrict__ aggp, float* __restrict__ headp, float* __restrict__ tailp)
{
  __shared__ float4 xs4[32*17];
  __shared__ float4 eas[FUSE ? 32*4 : 1];

  const int t = threadIdx.x;
  const int bid = ((blockIdx.x & 7) << 10) | (blockIdx.x >> 3);  // XCD swizzle, 8192 = 8*1024
  const int rowbase = bid*32;
  const int g = rowbase >> 12;
  const int wv = t>>6, lane = t&63, cl = lane&15, kgrp = lane>>4;
  const int sbase = rowbase + 16*wv;
  const int sid   = bid*2 + wv;
  const int lrow  = 16*wv + cl;
  const int grow0 = sbase + 4*kgrp;

  float b1c[4], b2c[4], lngc[4], lnbc[4], uec[4], ebc[4];
#pragma unroll
  for (int nt=0;nt<4;nt++){
    int cn = nt*16 + cl;
    b1c[nt] = b1[cn]; b2c[nt] = b2[cn];
    lngc[nt] = lng[cn]; lnbc[nt] = lnb[cn];
    uec[nt] = ue[(g<<6)+cn];
    if constexpr (FUSE) ebc[nt] = eb[cn]; else ebc[nt] = 0.f;
  }

  int4 sv = ((const int4*)srcs)[grow0>>2];
  int4 dv = ((const int4*)dsts)[grow0>>2];
  float exa[4][4], exb[4][4];
#pragma unroll
  for (int reg=0;reg<4;reg++){
    int s_ = ((const int*)&sv)[reg], d_ = ((const int*)&dv)[reg];
#pragma unroll
    for (int nt=0;nt<4;nt++){
      exa[reg][nt] = pa[(size_t)s_*64 + nt*16 + cl];
      exb[reg][nt] = pb[(size_t)d_*64 + nt*16 + cl];
    }
  }

  float* xsw = (float*)xs4;

  if constexpr (FUSE){
    {
      int r = lane>>2, q = lane&3;
      int e = eord[sbase + r];
      eas[(16*wv + r)*4 + q] = ((const float4*)(eattr + (size_t)e*16))[q];
    }
    f32x4 c0={0,0,0,0}, c1={0,0,0,0}, c2={0,0,0,0}, c3={0,0,0,0};
    short8b ahi, alo;
    if (kgrp < 2){
      float4 a0 = eas[(16*wv+cl)*4 + kgrp*2];
      float4 a1 = eas[(16*wv+cl)*4 + kgrp*2 + 1];
      mk_frag(a0, a1, ahi, alo);
    } else {
      ahi = (short8b){0,0,0,0,0,0,0,0};
      alo = (short8b){0,0,0,0,0,0,0,0};
    }
    const short8b* Wh = (const short8b*)weh;
    const short8b* Wl = (const short8b*)wel;
#pragma unroll
    for (int nt=0;nt<4;nt++){
      short8b bh = Wh[nt*64 + lane];
      short8b bl = Wl[nt*64 + lane];
      f32x4 c = (nt==0)?c0:(nt==1)?c1:(nt==2)?c2:c3;
      c = __builtin_amdgcn_mfma_f32_16x16x32_bf16(ahi, bh, c, 0,0,0);
      c = __builtin_amdgcn_mfma_f32_16x16x32_bf16(alo, bh, c, 0,0,0);
      c = __builtin_amdgcn_mfma_f32_16x16x32_bf16(ahi, bl, c, 0,0,0);
      if (nt==0) c0=c; else if (nt==1) c1=c; else if (nt==2) c2=c; else c3=c;
    }
#pragma unroll
    for (int nt=0;nt<4;nt++){
      int cn = nt*16 + cl;
      f32x4 c = (nt==0)?c0:(nt==1)?c1:(nt==2)?c2:c3;
#pragma unroll
      for (int reg=0;reg<4;reg++){
        float h = fmaxf(c[reg] + ebc[nt], 0.f);
        xsw[(16*wv + 4*kgrp + reg)*68 + cn] = h;
      }
    }
  } else {
    const float4* heb = (const float4*)(he + (size_t)rowbase*64);
#pragma unroll
    for (int it=0;it<4;it++){
      int r = 16*wv + (lane>>4) + it*4;
      xs4[r*17 + cl] = heb[r*16 + cl];
    }
  }

  const short8b* W1h = (const short8b*)w1h;
  const short8b* W1l = (const short8b*)w1l;
  const short8b* W2h = (const short8b*)w2h;
  const short8b* W2l = (const short8b*)w2l;

  // ---- GEMM1 ----
  f32x4 acc0 = {0,0,0,0}, acc1 = {0,0,0,0}, acc2_ = {0,0,0,0}, acc3 = {0,0,0,0};
#pragma unroll
  for (int kc=0;kc<2;kc++){
    float4 a0 = xs4[lrow*17 + kc*8 + kgrp*2];
    float4 a1 = xs4[lrow*17 + kc*8 + kgrp*2 + 1];
    short8b ahi, alo; mk_frag(a0, a1, ahi, alo);
#pragma unroll
    for (int nt=0;nt<4;nt++){
      short8b bh = W1h[(kc*4+nt)*64 + lane];
      short8b bl = W1l[(kc*4+nt)*64 + lane];
      f32x4 c = (nt==0)?acc0:(nt==1)?acc1:(nt==2)?acc2_:acc3;
      c = __builtin_amdgcn_mfma_f32_16x16x32_bf16(ahi, bh, c, 0,0,0);
      c = __builtin_amdgcn_mfma_f32_16x16x32_bf16(alo, bh, c, 0,0,0);
      c = __builtin_amdgcn_mfma_f32_16x16x32_bf16(ahi, bl, c, 0,0,0);
      if (nt==0) acc0=c; else if (nt==1) acc1=c; else if (nt==2) acc2_=c; else acc3=c;
    }
  }

  // ---- epilogue1: h1 ----
#pragma unroll
  for (int nt=0;nt<4;nt++){
    int cn = nt*16 + cl;
    float bc = b1c[nt] + uec[nt];
    f32x4 c = (nt==0)?acc0:(nt==1)?acc1:(nt==2)?acc2_:acc3;
#pragma unroll
    for (int reg=0;reg<4;reg++){
      float h = fmaxf(c[reg] + bc + exa[reg][nt] + exb[reg][nt], 0.f);
      xsw[(16*wv + 4*kgrp + reg)*68 + cn] = h;
    }
  }

  // ---- GEMM2 ----
  f32x4 d0 = {0,0,0,0}, d1 = {0,0,0,0}, d2 = {0,0,0,0}, d3 = {0,0,0,0};
#pragma unroll
  for (int kc=0;kc<2;kc++){
    float4 a0 = xs4[lrow*17 + kc*8 + kgrp*2];
    float4 a1 = xs4[lrow*17 + kc*8 + kgrp*2 + 1];
    short8b ahi, alo; mk_frag(a0, a1, ahi, alo);
#pragma unroll
    for (int nt=0;nt<4;nt++){
      short8b bh = W2h[(kc*4+nt)*64 + lane];
      short8b bl = W2l[(kc*4+nt)*64 + lane];
      f32x4 c = (nt==0)?d0:(nt==1)?d1:(nt==2)?d2:d3;
      c = __builtin_amdgcn_mfma_f32_16x16x32_bf16(ahi, bh, c, 0,0,0);
      c = __builtin_amdgcn_mfma_f32_16x16x32_bf16(alo, bh, c, 0,0,0);
      c = __builtin_amdgcn_mfma_f32_16x16x32_bf16(ahi, bl, c, 0,0,0);
      if (nt==0) d0=c; else if (nt==1) d1=c; else if (nt==2) d2=c; else d3=c;
    }
  }

  // ---- LayerNorm -> LDS (own rows) ----
#pragma unroll
  for (int reg=0;reg<4;reg++){
    float v0 = d0[reg] + b2c[0];
    float v1 = d1[reg] + b2c[1];
    float v2 = d2[reg] + b2c[2];
    float v3 = d3[reg] + b2c[3];
    float sA = v0+v1+v2+v3;
    float sB = v0*v0+v1*v1+v2*v2+v3*v3;
#pragma unroll
    for (int m=1;m<16;m<<=1){ sA += __shfl_xor(sA,m); sB += __shfl_xor(sB,m); }
    float mean = sA * 0.015625f;
    float var  = sB * 0.015625f - mean*mean;
    float inv  = 1.0f / sqrtf(var + 1e-5f);
    float* lr = xsw + (16*wv + 4*kgrp + reg)*68;
    lr[cl]    = (v0-mean)*inv*lngc[0] + lnbc[0];
    lr[16+cl] = (v1-mean)*inv*lngc[1] + lnbc[1];
    lr[32+cl] = (v2-mean)*inv*lngc[2] + lnbc[2];
    lr[48+cl] = (v3-mean)*inv*lngc[3] + lnbc[3];
  }

  // ---- he store (own rows, coalesced float4) ----
  if constexpr (WRITE_HE){
    float4* he4 = (float4*)outp;
#pragma unroll
    for (int it=0;it<4;it++){
      int r = 16*wv + (lane>>4) + it*4;
      he4[(size_t)rowbase*16 + r*16 + cl] = xs4[r*17 + cl];
    }
  }

  // ---- per-slice deterministic aggregation (same-wave LDS, no barrier) ----
  {
    int n0 = dsts[sbase], nL = dsts[sbase+15];
    const int s = lane>>4, cq2 = lane&15;
    for (int n = n0 + s; n <= nL; n += 4){
      int lo = indptr[n], hi = indptr[n+1];
      int lo_c = lo - sbase; if (lo_c < 0) lo_c = 0;
      int hi_c = hi - sbase; if (hi_c > 16) hi_c = 16;
      float4 a = {0,0,0,0};
      for (int p = lo_c; p < hi_c; ++p){
        float4 v = xs4[(16*wv+p)*17 + cq2];
        a.x += v.x; a.y += v.y; a.z += v.z; a.w += v.w;
      }
      if (lo < sbase)            ((float4*)(headp + (size_t)sid*64))[cq2] = a;
      else if (hi > sbase + 16)  ((float4*)(tailp + (size_t)sid*64))[cq2] = a;
      else                       ((float4*)(aggp + (size_t)n*64))[cq2] = a;
    }
    if (s == 0 && !(indptr[n0] < sbase)){
      float4 z = {0,0,0,0};
      ((float4*)(headp + (size_t)sid*64))[cq2] = z;
    }
    if (s == 1){
      int lo = indptr[nL], hi = indptr[nL+1];
      if (!(lo >= sbase && hi > sbase + 16)){
        float4 z = {0,0,0,0};
        ((float4*)(tailp + (size_t)sid*64))[cq2] = z;
      }
    }
  }
}

// ---------------- node MLP: barrier-free, per-wave 16-node slices ----------------
template<int PREP>
__global__ __launch_bounds__(256) void node_mlp_mfma(
    const float* __restrict__ hn, const float* __restrict__ agg,
    const float* __restrict__ un,
    const int* __restrict__ indptr,
    const float* __restrict__ headp, const float* __restrict__ tailp,
    const short* __restrict__ w1h, const short* __restrict__ w1l,
    const short* __restrict__ w2h, const short* __restrict__ w2l,
    const short* __restrict__ wah, const short* __restrict__ wal,
    const short* __restrict__ wbh, const short* __restrict__ wbl,
    const float* __restrict__ b1, const float* __restrict__ b2,
    const float* __restrict__ lng, const float* __restrict__ lnb,
    float* __restrict__ outp, float* __restrict__ pn, float* __restrict__ pe,
    float* __restrict__ pa, float* __restrict__ pb)
{
  __shared__ float4 xs4[64*33];

  const int t = threadIdx.x;
  const int bid = ((blockIdx.x & 7) << 6) | (blockIdx.x >> 3);
  const int rowbase = bid*64;
  const int g = rowbase >> 9;
  const int wv = t>>6, lane = t&63, cl = lane&15, kgrp = lane>>4;
  const int sid   = bid*4 + wv;
  const int lrow  = 16*wv + cl;
  const int grow0 = rowbase + 16*wv + 4*kgrp;

  float b1c[4], b2c[4], lngc[4], lnbc[4], unc[4];
#pragma unroll
  for (int nt=0;nt<4;nt++){
    int cn = nt*16 + cl;
    b1c[nt] = b1[cn]; b2c[nt] = b2[cn];
    lngc[nt] = lng[cn]; lnbc[nt] = lnb[cn];
    unc[nt] = un[(g<<6)+cn];
  }

  {
    const float4* hn4 = (const float4*)(hn + (size_t)rowbase*64);
#pragma unroll
    for (int it=0;it<4;it++){
      int r = 16*wv + (lane>>4) + it*4;
      xs4[r*33 + cl] = hn4[r*16 + cl];
    }
  }
  float4 easum = {0,0,0,0};
  {
#pragma unroll
    for (int it=0;it<4;it++){
      int r = 16*wv + (lane>>4) + it*4;
      int n = rowbase + r;
      int lo = indptr[n], hi = indptr[n+1];
      float4 a = {0,0,0,0};
      if (lo < hi){
        int s0 = lo >> 4, s1 = (hi-1) >> 4;
        if (s0 == s1){
          a = ((const float4*)(agg + (size_t)n*64))[cl];
        } else {
          a = ((const float4*)(tailp + (size_t)s0*64))[cl];
          for (int s = s0+1; s <= s1; ++s){
            float4 h = ((const float4*)(headp + (size_t)s*64))[cl];
            a.x+=h.x; a.y+=h.y; a.z+=h.z; a.w+=h.w;
          }
        }
      }
      xs4[r*33 + 16 + cl] = a;
      easum.x += a.x; easum.y += a.y; easum.z += a.z; easum.w += a.w;
    }
    easum.x += __shfl_xor(easum.x,16); easum.x += __shfl_xor(easum.x,32);
    easum.y += __shfl_xor(easum.y,16); easum.y += __shfl_xor(easum.y,32);
    easum.z += __shfl_xor(easum.z,16); easum.z += __shfl_xor(easum.z,32);
    easum.w += __shfl_xor(easum.w,16); easum.w += __shfl_xor(easum.w,32);
    if (kgrp == 0) ((float4*)(pe + (size_t)sid*64))[cl] = easum;
  }

  const short8b* W1h = (const short8b*)w1h;
  const short8b* W1l = (const short8b*)w1l;
  const short8b* W2h = (const short8b*)w2h;
  const short8b* W2l = (const short8b*)w2l;

  // ---- GEMM1 (K=128) ----
  f32x4 acc0 = {0,0,0,0}, acc1 = {0,0,0,0}, acc2_ = {0,0,0,0}, acc3 = {0,0,0,0};
#pragma unroll
  for (int kc=0;kc<4;kc++){
    float4 a0 = xs4[lrow*33 + kc*8 + kgrp*2];
    float4 a1 = xs4[lrow*33 + kc*8 + kgrp*2 + 1];
    short8b ahi, alo; mk_frag(a0, a1, ahi, alo);
#pragma unroll
    for (int nt=0;nt<4;nt++){
      short8b bh = W1h[(kc*4+nt)*64 + lane];
      short8b bl = W1l[(kc*4+nt)*64 + lane];
      f32x4 c = (nt==0)?acc0:(nt==1)?acc1:(nt==2)?acc2_:acc3;
      c = __builtin_amdgcn_mfma_f32_16x16x32_bf16(ahi, bh, c, 0,0,0);
      c = __builtin_amdgcn_mfma_f32_16x16x32_bf16(alo, bh, c, 0,0,0);
      c = __builtin_amdgcn_mfma_f32_16x16x32_bf16(ahi, bl, c, 0,0,0);
      if (nt==0) acc0=c; else if (nt==1) acc1=c; else if (nt==2) acc2_=c; else acc3=c;
    }
  }

  float* xsw = (float*)xs4;
#pragma unroll
  for (int nt=0;nt<4;nt++){
    int cn = nt*16 + cl;
    float bc = b1c[nt] + unc[nt];
    f32x4 c = (nt==0)?acc0:(nt==1)?acc1:(nt==2)?acc2_:acc3;
#pragma unroll
    for (int reg=0;reg<4;reg++){
      float h = fmaxf(c[reg] + bc, 0.f);
      xsw[(16*wv + 4*kgrp + reg)*132 + cn] = h;
    }
  }

  // ---- GEMM2 (K=64) ----
  f32x4 d0 = {0,0,0,0}, d1 = {0,0,0,0}, d2 = {0,0,0,0}, d3 = {0,0,0,0};
#pragma unroll
  for (int kc=0;kc<2;kc++){
    float4 a0 = xs4[lrow*33 + kc*8 + kgrp*2];
    float4 a1 = xs4[lrow*33 + kc*8 + kgrp*2 + 1];
    short8b ahi, alo; mk_frag(a0, a1, ahi, alo);
#pragma unroll
    for (int nt=0;nt<4;nt++){
      short8b bh = W2h[(kc*4+nt)*64 + lane];
      short8b bl = W2l[(kc*4+nt)*64 + lane];
      f32x4 c = (nt==0)?d0:(nt==1)?d1:(nt==2)?d2:d3;
      c = __builtin_amdgcn_mfma_f32_16x16x32_bf16(ahi, bh, c, 0,0,0);
      c = __builtin_amdgcn_mfma_f32_16x16x32_bf16(alo, bh, c, 0,0,0);
      c = __builtin_amdgcn_mfma_f32_16x16x32_bf16(ahi, bl, c, 0,0,0);
      if (nt==0) d0=c; else if (nt==1) d1=c; else if (nt==2) d2=c; else d3=c;
    }
  }

  // ---- LayerNorm -> LDS (own rows) + pn partial ----
  float ms0 = 0.f, ms1 = 0.f, ms2 = 0.f, ms3 = 0.f;
#pragma unroll
  for (int reg=0;reg<4;reg++){
    float v0 = d0[reg] + b2c[0];
    float v1 = d1[reg] + b2c[1];
    float v2 = d2[reg] + b2c[2];
    float v3 = d3[reg] + b2c[3];
    float sA = v0+v1+v2+v3;
    float sB = v0*v0+v1*v1+v2*v2+v3*v3;
#pragma unroll
    for (int m=1;m<16;m<<=1){ sA += __shfl_xor(sA,m); sB += __shfl_xor(sB,m); }
    float mean = sA * 0.015625f;
    float var  = sB * 0.015625f - mean*mean;
    float inv  = 1.0f / sqrtf(var + 1e-5f);
    float o0v = (v0-mean)*inv*lngc[0] + lnbc[0];
    float o1v = (v1-mean)*inv*lngc[1] + lnbc[1];
    float o2v = (v2-mean)*inv*lngc[2] + lnbc[2];
    float o3v = (v3-mean)*inv*lngc[3] + lnbc[3];
    float* lr = xsw + (16*wv + 4*kgrp + reg)*132;
    lr[cl] = o0v; lr[16+cl] = o1v; lr[32+cl] = o2v; lr[48+cl] = o3v;
    ms0 += o0v; ms1 += o1v; ms2 += o2v; ms3 += o3v;
  }
  ms0 += __shfl_xor(ms0,16); ms0 += __shfl_xor(ms0,32);
  ms1 += __shfl_xor(ms1,16); ms1 += __shfl_xor(ms1,32);
  ms2 += __shfl_xor(ms2,16); ms2 += __shfl_xor(ms2,32);
  ms3 += __shfl_xor(ms3,16); ms3 += __shfl_xor(ms3,32);
  if (kgrp == 0){
    pn[(size_t)sid*64 + cl]      = ms0;
    pn[(size_t)sid*64 + 16 + cl] = ms1;
    pn[(size_t)sid*64 + 32 + cl] = ms2;
    pn[(size_t)sid*64 + 48 + cl] = ms3;
  }

  {
    float4* hn4o = (float4*)outp;
#pragma unroll
    for (int it=0;it<4;it++){
      int r = 16*wv + (lane>>4) + it*4;
      hn4o[(size_t)rowbase*16 + r*16 + cl] = xs4[r*33 + cl];
    }
  }

  if constexpr (PREP){
#pragma unroll
    for (int m2=0;m2<2;m2++){
      const short8b* Wh = (const short8b*)(m2==0 ? wah : wbh);
      const short8b* Wl = (const short8b*)(m2==0 ? wal : wbl);
      f32x4 e0 = {0,0,0,0}, e1 = {0,0,0,0}, e2 = {0,0,0,0}, e3 = {0,0,0,0};
#pragma unroll
      for (int kc=0;kc<2;kc++){
        float4 a0 = xs4[lrow*33 + kc*8 + kgrp*2];
        float4 a1 = xs4[lrow*33 + kc*8 + kgrp*2 + 1];
        short8b ahi, alo; mk_frag(a0, a1, ahi, alo);
#pragma unroll
        for (int nt=0;nt<4;nt++){
          short8b bh = Wh[(kc*4+nt)*64 + lane];
          short8b bl = Wl[(kc*4+nt)*64 + lane];
          f32x4 c = (nt==0)?e0:(nt==1)?e1:(nt==2)?e2:e3;
          c = __builtin_amdgcn_mfma_f32_16x16x32_bf16(ahi, bh, c, 0,0,0);
          c = __builtin_amdgcn_mfma_f32_16x16x32_bf16(alo, bh, c, 0,0,0);
          c = __builtin_amdgcn_mfma_f32_16x16x32_bf16(ahi, bl, c, 0,0,0);
          if (nt==0) e0=c; else if (nt==1) e1=c; else if (nt==2) e2=c; else e3=c;
        }
      }
      float* dstp = (m2==0) ? pa : pb;
#pragma unroll
      for (int nt=0;nt<4;nt++){
        int cn = nt*16 + cl;
        f32x4 c = (nt==0)?e0:(nt==1)?e1:(nt==2)?e2:e3;
#pragma unroll
        for (int reg=0;reg<4;reg++)
          dstp[(size_t)(grow0+reg)*64 + cn] = c[reg];
      }
    }
  }
}

// ---------------- graphk: means reduce (32 chunks) + graph MLP + LN + next ue/un ----------------
__global__ __launch_bounds__(64) void graphk(
    const float* __restrict__ pn, const float* __restrict__ pe,
    float* __restrict__ u,
    const float* __restrict__ w1, const float* __restrict__ b1,
    const float* __restrict__ w2, const float* __restrict__ b2,
    const float* __restrict__ lng, const float* __restrict__ lnb,
    const float* __restrict__ wue, const float* __restrict__ wun,
    float* __restrict__ ue, float* __restrict__ un)
{
  const int g = blockIdx.x, t = threadIdx.x;
  __shared__ float xin[192];
  __shared__ float h1[64];
  __shared__ float us[64];
  float uo = u[(g<<6)+t];
  float ns = 0.f, es = 0.f;
#pragma unroll
  for (int c=0;c<32;c++){
    ns += pn[(size_t)(g*32+c)*64 + t];
    es += pe[(size_t)(g*32+c)*64 + t];
  }
  xin[t] = uo; xin[64+t] = ns*(1.f/512.f); xin[128+t] = es*(1.f/4096.f);
  __syncthreads();
  float acc = b1[t];
  for (int k=0;k<192;k++) acc = fmaf(xin[k], w1[k*64+t], acc);
  h1[t] = fmaxf(acc, 0.f);
  __syncthreads();
  float v = b2[t];
  for (int k=0;k<64;k++) v = fmaf(h1[k], w2[k*64+t], v);
  float sA = v, sB = v*v;
#pragma unroll
  for (int m=1;m<64;m<<=1){ sA += __shfl_xor(sA,m); sB += __shfl_xor(sB,m); }
  float mean = sA * 0.015625f;
  float var  = sB * 0.015625f - mean*mean;
  float inv  = 1.0f / sqrtf(var + 1e-5f);
  float unew = (v-mean)*inv*lng[t] + lnb[t];
  u[(g<<6)+t] = unew;
  if (wue){
    us[t] = unew;
    __syncthreads();
    float a1 = 0.f, a2 = 0.f;
    for (int k=0;k<64;k++){
      float xv = us[k];
      a1 = fmaf(xv, wue[k*64+t], a1);
      a2 = fmaf(xv, wun[k*64+t], a2);
    }
    ue[(g<<6)+t] = a1;
    un[(g<<6)+t] = a2;
  }
}

// ---------------- heads ----------------
__global__ __launch_bounds__(512) void heads_kernel(
    const float* __restrict__ hn, const float* __restrict__ uvec,
    const float* __restrict__ aw, const float* __restrict__ ab,
    const float* __restrict__ cw, const float* __restrict__ cb,
    float* __restrict__ out)
{
  const int g = blockIdx.x, t = threadIdx.x;
  const int n = (g<<9) + t;
  const float4* hp = (const float4*)(hn + (size_t)n*64);
  const float4* ap = (const float4*)aw;
  float d = 0.f;
#pragma unroll
  for (int i=0;i<16;i++){
    float4 h = hp[i], a = ap[i];
    d += h.x*a.x + h.y*a.y + h.z*a.z + h.w*a.w;
  }
  d += ab[0];
  float z = 1.0f/(1.0f + expf(-d));

  unsigned o0,o1;
  threefry(0u, 42u, 0u, (unsigned)n, o0, o1);
  unsigned bits = o0 ^ o1;
  float f = __uint_as_float((bits>>9) | 0x3f800000u) - 1.0f;
  float gum = -logf(-logf(fmaxf(1.17549435e-38f, f)));

  const int lane = t & 63, wid = t >> 6;
  __shared__ float smax[8], ssum[8], sent[8], skey[8];
  __shared__ int   sidx[8];
  __shared__ float sM, sS;
  __shared__ int   sA;

  float m = z;
#pragma unroll
  for (int sh=1; sh<64; sh<<=1) m = fmaxf(m, __shfl_xor(m, sh));
  if (lane==0) smax[wid] = m;
  __syncthreads();
  if (t==0){ float mm=smax[0]; for(int i=1;i<8;i++) mm=fmaxf(mm,smax[i]); sM=mm; }
  __syncthreads();
  float M = sM;
  float ex = expf(z - M);
  float ssl = ex;
#pragma unroll
  for (int sh=1; sh<64; sh<<=1) ssl += __shfl_xor(ssl, sh);
  if (lane==0) ssum[wid] = ssl;
  __syncthreads();
  if (t==0){ float ss=0.f; for(int i=0;i<8;i++) ss+=ssum[i]; sS=ss; }
  __syncthreads();
  float logp = z - M - logf(sS);
  float p = expf(logp);
  float entl = p * logp;
#pragma unroll
  for (int sh=1; sh<64; sh<<=1) entl += __shfl_xor(entl, sh);
  if (lane==0) sent[wid] = entl;

  float kv = z + gum; int ki = t;
#pragma unroll
  for (int sh=1; sh<64; sh<<=1){
    float ov = __shfl_xor(kv, sh);
    int   oi = __shfl_xor(ki, sh);
    if (ov > kv || (ov == kv && oi < ki)){ kv = ov; ki = oi; }
  }
  if (lane==0){ skey[wid] = kv; sidx[wid] = ki; }
  __syncthreads();
  if (t==0){
    float bv = skey[0]; int bi = sidx[0];
    for (int i=1;i<8;i++) if (skey[i] > bv || (skey[i]==bv && sidx[i] < bi)){ bv=skey[i]; bi=sidx[i]; }
    sA = bi;
    float ent = 0.f; for (int i=0;i<8;i++) ent += sent[i];
    out[g]      = (float)bi;
    out[128+g]  = -ent;
  }
  __syncthreads();
  if (t == sA) out[64+g] = logp;

  if (t < 64){
    float pv = uvec[(g<<6)+t] * cw[t];
#pragma unroll
    for (int sh=1; sh<64; sh<<=1) pv += __shfl_xor(pv, sh);
    if (t==0) out[192+g] = pv + cb[0];
  }
}

// ---------------- launch ----------------
extern "C" void kernel_launch(void* const* d_in, const int* in_sizes, int n_in,
                              void* d_out, int out_size, void* d_ws, size_t ws_size,
                              hipStream_t stream)
{
  (void)in_sizes; (void)n_in; (void)out_size; (void)ws_size;
  const float* x      = (const float*)d_in[0];
  const float* eattr  = (const float*)d_in[1];
  const int*   eidx   = (const int*)d_in[2];
  const float* node_w = (const float*)d_in[5];
  const float* node_b = (const float*)d_in[6];
  const float* edge_w = (const float*)d_in[7];
  const float* edge_b = (const float*)d_in[8];
  const float* init_u = (const float*)d_in[9];
  const float* ew1 = (const float*)d_in[10]; const float* eb1 = (const float*)d_in[11];
  const float* ew2 = (const float*)d_in[12]; const float* eb2 = (const float*)d_in[13];
  const float* elg = (const float*)d_in[14]; const float* elb = (const float*)d_in[15];
  const float* nw1 = (const float*)d_in[16]; const float* nb1 = (const float*)d_in[17];
  const float* nw2 = (const float*)d_in[18]; const float* nb2 = (const float*)d_in[19];
  const float* nlg = (const float*)d_in[20]; const float* nlb = (const float*)d_in[21];
  const float* gw1 = (const float*)d_in[22]; const float* gb1 = (const float*)d_in[23];
  const float* gw2 = (const float*)d_in[24]; const float* gb2 = (const float*)d_in[25];
  const float* glg = (const float*)d_in[26]; const float* glb = (const float*)d_in[27];
  const float* aw  = (const float*)d_in[28]; const float* ab  = (const float*)d_in[29];
  const float* cw  = (const float*)d_in[30]; const float* cb  = (const float*)d_in[31];
  const int* src = eidx;
  const int* dst = eidx + EE;

  float* ws    = (float*)d_ws;
  float* hn    = ws;                         // N*64
  float* he    = hn + (size_t)NN*64;         // E*64  (dst-sorted order)
  float* agg   = he + (size_t)EE*64;         // N*64
  float* u     = agg + (size_t)NN*64;        // G*64
  int* cnt     = (int*)(u + GG*64);          // N
  int* indptr  = cnt + NN;                   // N+1
  int* fillc   = indptr + NN + 1;            // N
  int* eord    = fillc + NN;                 // E
  int* srcs    = eord + EE;                  // E
  int* dsts    = srcs + EE;                  // E
  float* pb    = (float*)(dsts + EE);        // N*64
  float* pa    = pb + (size_t)NN*64;         // N*64
  float* ue    = pa + (size_t)NN*64;         // G*64
  float* un    = ue + GG*64;                 // G*64
  float* pn    = un + GG*64;                 // 2048*64
  float* pe    = pn + 2048*64;               // 2048*64
  float* headp = pe + 2048*64;               // 16384*64
  float* tailp = headp + (size_t)16384*64;   // 16384*64
  short* wfh   = (short*)(tailp + (size_t)16384*64);  // 88064 shorts
  short* wfl   = wfh + 88064;                // 88064 shorts

  float* out = (float*)d_out;

  hipMemsetAsync(cnt,   0, NN*sizeof(int), stream);
  hipMemsetAsync(fillc, 0, NN*sizeof(int), stream);

  count_kernel<<<EE/256, 256, 0, stream>>>(dst, cnt);
  scan_kernel<<<1, 1024, 0, stream>>>(cnt, indptr);
  fill_kernel<<<EE/256, 256, 0, stream>>>(dst, indptr, fillc, eord);
  sort_kernel<<<NN/256, 256, 0, stream>>>(indptr, eord, src, dst, srcs, dsts);

  // fused node encode + layer-0 pa/pb
  encode_pre_kernel<<<NN/32, 256, 0, stream>>>(x, node_w, node_b,
      ew1, ew1 + 64*64, hn, pa, pb);
  initu_kernel<<<16, 256, 0, stream>>>(init_u, u);
  wprep_kernel<<<43, 256, 0, stream>>>(edge_w, ew1, ew2, nw1, nw2, wfh, wfl);
  pre_kernel<<<2, 256, 0, stream>>>(u, ew1 + 192*64, nw1 + 128*64, ue, un, GG);

  // frag offsets (shorts): enc=0; per layer l: e1=2048+l*20480, e2=+4096, n1=+8192, n2=+16384
  // prep frags: pa(l)=63488+l*8192, pb(l)=+4096
  for (int l=0; l<NL; ++l){
    size_t e1o = 2048 + (size_t)l*20480;
    size_t e2o = e1o + 4096, n1o = e1o + 8192, n2o = e1o + 16384;
    size_t pao = 63488 + (size_t)(l+1)*8192, pbo = pao + 4096;  // next layer

    if (l == 0)
      edge_mlp_mfma<1,1><<<EE/32, 128, 0, stream>>>(he, eattr, eord, pa, pb, ue, srcs, dsts, indptr,
          wfh, wfl, wfh + e1o, wfl + e1o, wfh + e2o, wfl + e2o,
          edge_b, eb1 + l*64, eb2 + l*64, elg + l*64, elb + l*64, he, agg, headp, tailp);
    else if (l == 1)
      edge_mlp_mfma<0,1><<<EE/32, 128, 0, stream>>>(he, eattr, eord, pa, pb, ue, srcs, dsts, indptr,
          wfh, wfl, wfh + e1o, wfl + e1o, wfh + e2o, wfl + e2o,
          edge_b, eb1 + l*64, eb2 + l*64, elg + l*64, elb + l*64, he, agg, headp, tailp);
    else
      edge_mlp_mfma<0,0><<<EE/32, 128, 0, stream>>>(he, eattr, eord, pa, pb, ue, srcs, dsts, indptr,
          wfh, wfl, wfh + e1o, wfl + e1o, wfh + e2o, wfl + e2o,
          edge_b, eb1 + l*64, eb2 + l*64, elg + l*64, elb + l*64, he, agg, headp, tailp);

    if (l < NL-1)
      node_mlp_mfma<1><<<NN/64, 256, 0, stream>>>(hn, agg, un, indptr, headp, tailp,
          wfh + n1o, wfl + n1o, wfh + n2o, wfl + n2o,
          wfh + pao, wfl + pao, wfh + pbo, wfl + pbo,
          nb1 + l*64, nb2 + l*64, nlg + l*64, nlb + l*64, hn, pn, pe, pa, pb);
    else
      node_mlp_mfma<0><<<NN/64, 256, 0, stream>>>(hn, agg, un, indptr, headp, tailp,
          wfh + n1o, wfl + n1o, wfh + n2o, wfl + n2o,
          nullptr, nullptr, nullptr, nullptr,
          nb1 + l*64, nb2 + l*64, nlg + l*64, nlb + l*64, hn, pn, pe, pa, pb);

    const float* wue = (l < NL-1) ? (ew1 + (size_t)(l+1)*16384 + 192*64) : nullptr;
    const float* wun = (l < NL-1) ? (nw1 + (size_t)(l+1)*12288 + 128*64) : nullptr;
    graphk<<<GG, 64, 0, stream>>>(pn, pe, u,
        gw1 + (size_t)l*192*64, gb1 + l*64, gw2 + (size_t)l*64*64, gb2 + l*64,
        glg + l*64, glb + l*64, wue, wun, ue, un);
  }

  heads_kernel<<<GG, 512, 0, stream>>>(hn, u, aw, ab, cw, cb, out);
}